// Round 1
// baseline (966.417 us; speedup 1.0000x reference)
//
#include <hip/hip_runtime.h>

namespace {

constexpr int T   = 512;   // sequence length
constexpr int H   = 64;    // hidden
constexpr int BPB = 4;     // batches per block
constexpr int TPB = 256;   // threads per block (4 waves)

__device__ __forceinline__ float fsig(float x) {
  // 1/(1+e^-x); v_exp + v_rcp (~1e-7 rel err, fine vs 9.2e-4 threshold)
  return __builtin_amdgcn_rcpf(1.0f + __expf(-x));
}
__device__ __forceinline__ float ftanh(float x) {
  // tanh(x) = 1 - 2/(1+e^{2x}); saturates gracefully on exp over/underflow
  return fmaf(-2.0f, __builtin_amdgcn_rcpf(1.0f + __expf(2.0f * x)), 1.0f);
}
__device__ __forceinline__ float dot4(float4 w, float4 h, float a) {
  a = fmaf(w.x, h.x, a);
  a = fmaf(w.y, h.y, a);
  a = fmaf(w.z, h.z, a);
  return fmaf(w.w, h.w, a);
}

// grid 512 x block 256. Each block: 4 batch elements, all 64 units.
// wave w owns units [16w,16w+16); lane = (uu<<2)|bb : unit uu, batch bb.
// W_hh k in [0,32) lives in 128 VGPRs per lane; k in [32,64) in LDS
// (row stride 36 floats -> 16B-aligned b128 reads, bank-quads spread).
__global__ __launch_bounds__(TPB, 1)
void lstm_fused(const float* __restrict__ xg,
                const float* __restrict__ W_ih,
                const float* __restrict__ W_hh,
                const float* __restrict__ b_ih,
                const float* __restrict__ b_hh,
                const float* __restrict__ fc1_w,
                const float* __restrict__ fc1_b,
                const float* __restrict__ fc2_w,
                const float* __restrict__ fc2_b,
                float* __restrict__ out)
{
  __shared__ __align__(16) float Wl[256 * 36];        // W_hh[:, 32:64], stride 36
  __shared__ __align__(16) float xs[BPB][T + 4];      // +4 pad: avoid 4-way bank hit
  __shared__ __align__(16) float hbuf[2][BPB][68];    // stride 68: bank spread
  __shared__ float zs[BPB][16];

  const int tid = threadIdx.x;
  const int b0  = blockIdx.x * BPB;

  // ---- stage W_hh upper-k half into LDS (one row per thread) ----
  {
    const int row = tid;  // 256 rows, 256 threads
    const float4* src = (const float4*)(W_hh + row * H + 32);
#pragma unroll
    for (int kg = 0; kg < 8; ++kg) {
      *(float4*)&Wl[row * 36 + kg * 4] = src[kg];
    }
  }
  // ---- stage x for this block's 4 batches ----
  for (int i = tid; i < BPB * T / 4; i += TPB) {
    const int xb = i >> 7;          // batch 0..3
    const int tq = i & 127;         // float4 index within row
    float4 v = ((const float4*)(xg + (size_t)(b0 + xb) * T))[tq];
    *(float4*)&xs[xb][tq * 4] = v;
  }
  // ---- zero h double-buffer ----
  for (int i = tid; i < 2 * BPB * 68; i += TPB) ((float*)hbuf)[i] = 0.0f;

  // ---- per-lane setup ----
  const int lane = tid & 63;
  const int wv   = tid >> 6;
  const int uu   = lane >> 2;
  const int bb   = lane & 3;
  const int u    = wv * 16 + uu;

  const int row_i = u;            // PyTorch gate order: i, f, g, o
  const int row_f = H + u;
  const int row_g = 2 * H + u;
  const int row_o = 3 * H + u;

  float4 wreg[4][8];              // 128 VGPRs: W_hh[rows][k<32]
  {
    const int rows[4] = {row_i, row_f, row_g, row_o};
#pragma unroll
    for (int g = 0; g < 4; ++g) {
      const float4* src = (const float4*)(W_hh + rows[g] * H);
#pragma unroll
      for (int kk = 0; kk < 8; ++kk) wreg[g][kk] = src[kk];
    }
  }
  const float wih0 = W_ih[row_i], wih1 = W_ih[row_f];
  const float wih2 = W_ih[row_g], wih3 = W_ih[row_o];
  const float bia0 = b_ih[row_i] + b_hh[row_i];
  const float bia1 = b_ih[row_f] + b_hh[row_f];
  const float bia2 = b_ih[row_g] + b_hh[row_g];
  const float bia3 = b_ih[row_o] + b_hh[row_o];

  const float* wp0 = &Wl[row_i * 36];
  const float* wp1 = &Wl[row_f * 36];
  const float* wp2 = &Wl[row_g * 36];
  const float* wp3 = &Wl[row_o * 36];

  float c = 0.0f;

  __syncthreads();  // staging + zeroed h visible

  for (int t = 0; t < T; ++t) {
    const float* hr = &hbuf[t & 1][bb][0];
    const float xt = xs[bb][t];
    float a0 = fmaf(xt, wih0, bia0);
    float a1 = fmaf(xt, wih1, bia1);
    float a2 = fmaf(xt, wih2, bia2);
    float a3 = fmaf(xt, wih3, bia3);
#pragma unroll
    for (int kg = 0; kg < 8; ++kg) {          // k in [0,32): W from VGPRs
      const float4 h4 = *(const float4*)(hr + kg * 4);
      a0 = dot4(wreg[0][kg], h4, a0);
      a1 = dot4(wreg[1][kg], h4, a1);
      a2 = dot4(wreg[2][kg], h4, a2);
      a3 = dot4(wreg[3][kg], h4, a3);
    }
#pragma unroll
    for (int kg = 0; kg < 8; ++kg) {          // k in [32,64): W from LDS
      const float4 h4 = *(const float4*)(hr + 32 + kg * 4);
      a0 = dot4(*(const float4*)(wp0 + kg * 4), h4, a0);
      a1 = dot4(*(const float4*)(wp1 + kg * 4), h4, a1);
      a2 = dot4(*(const float4*)(wp2 + kg * 4), h4, a2);
      a3 = dot4(*(const float4*)(wp3 + kg * 4), h4, a3);
    }
    const float ig = fsig(a0);
    const float fg = fsig(a1);
    const float gg = ftanh(a2);
    const float og = fsig(a3);
    c = fmaf(fg, c, ig * gg);
    const float hn = og * ftanh(c);
    hbuf[(t + 1) & 1][bb][u] = hn;
    __syncthreads();  // one barrier/step (double-buffered h)
  }

  // final h is in hbuf[0] (last write at t=511 targets buffer 0)
  // head: z = relu(h @ fc1^T + b1); out = z @ fc2^T + b2
  if (tid < BPB * 16) {
    const int bq = tid >> 4;
    const int j2 = tid & 15;
    float s = fc1_b[j2];
    const float* fw = fc1_w + j2 * H;
#pragma unroll
    for (int k = 0; k < H; ++k) s = fmaf(hbuf[0][bq][k], fw[k], s);
    s = fmaxf(s, 0.0f);
    zs[bq][j2] = s * fc2_w[j2];
  }
  __syncthreads();
  if (tid < BPB) {
    float s = fc2_b[0];
#pragma unroll
    for (int j = 0; j < 16; ++j) s += zs[tid][j];
    out[b0 + tid] = s;
  }
}

}  // namespace

extern "C" void kernel_launch(void* const* d_in, const int* in_sizes, int n_in,
                              void* d_out, int out_size, void* d_ws, size_t ws_size,
                              hipStream_t stream) {
  const float* xg    = (const float*)d_in[0];
  const float* W_ih  = (const float*)d_in[1];
  const float* W_hh  = (const float*)d_in[2];
  const float* b_ih  = (const float*)d_in[3];
  const float* b_hh  = (const float*)d_in[4];
  const float* fc1_w = (const float*)d_in[5];
  const float* fc1_b = (const float*)d_in[6];
  const float* fc2_w = (const float*)d_in[7];
  const float* fc2_b = (const float*)d_in[8];
  float* out = (float*)d_out;

  dim3 grid(2048 / BPB);   // 512 blocks -> 2 per CU
  dim3 block(TPB);
  hipLaunchKernelGGL(lstm_fused, grid, block, 0, stream,
                     xg, W_ih, W_hh, b_ih, b_hh, fc1_w, fc1_b, fc2_w, fc2_b, out);
}

// Round 2
// 720.328 us; speedup vs baseline: 1.3416x; 1.3416x over previous
//
#include <hip/hip_runtime.h>

namespace {

constexpr int T    = 512;   // sequence length
constexpr int H    = 64;    // hidden units
constexpr int TPB  = 256;   // 4 waves
constexpr int HSTR = 68;    // h row stride in floats (pad: 68*4B = 17*16B, 16B-aligned)

// DPP quad_perm controls: ctrl = a | b<<2 | c<<4 | d<<6
constexpr int QP_XOR1 = 0xB1;  // [1,0,3,2]
constexpr int QP_XOR2 = 0x4E;  // [2,3,0,1]

__device__ __forceinline__ float fsig(float x) {
  return __builtin_amdgcn_rcpf(1.0f + __expf(-x));
}
__device__ __forceinline__ float ftanh(float x) {
  return fmaf(-2.0f, __builtin_amdgcn_rcpf(1.0f + __expf(2.0f * x)), 1.0f);
}
__device__ __forceinline__ float dot4(float4 w, float4 h, float a) {
  a = fmaf(w.x, h.x, a);
  a = fmaf(w.y, h.y, a);
  a = fmaf(w.z, h.z, a);
  return fmaf(w.w, h.w, a);
}
// v += value-from-lane (lane ^ mask within quad); VALU-pipe cross-lane (no LDS)
template <int CTRL>
__device__ __forceinline__ float qadd(float v) {
  int x = __builtin_amdgcn_update_dpp(0, __float_as_int(v), CTRL, 0xf, 0xf, true);
  return v + __int_as_float(x);
}

// grid 512 x block 256; block = 4 batches x 64 units.
// thread: u = tid>>2 (unit), q = tid&3 (k-quarter AND batch for the c/h state).
// W_hh rows {u,64+u,128+u,192+u} x k in [16q,16q+16) live in 64 VGPRs per lane.
// Per step: 16 ds_read_b128 (h slices, 2-way/broadcast patterns = conflict-free),
// quad_perm DPP butterfly reduction (VALU), 1 ds_write_b32, 1 barrier.
__global__ __launch_bounds__(TPB, 2)
void lstm_fused(const float* __restrict__ xg,
                const float* __restrict__ W_ih,
                const float* __restrict__ W_hh,
                const float* __restrict__ b_ih,
                const float* __restrict__ b_hh,
                const float* __restrict__ fc1_w,
                const float* __restrict__ fc1_b,
                const float* __restrict__ fc2_w,
                const float* __restrict__ fc2_b,
                float* __restrict__ out)
{
  __shared__ __align__(16) float hs0[4 * HSTR];   // h double-buffer, layout [b][HSTR]
  __shared__ __align__(16) float hs1[4 * HSTR];
  __shared__ __align__(16) float xs[4][T + 4];    // +4 pad -> xs[q][t] reads hit 4 banks
  __shared__ float zs[4][16];

  const int tid = threadIdx.x;
  const int b0  = blockIdx.x * 4;
  const int u   = tid >> 2;
  const int q   = tid & 3;

  // ---- stage x (coalesced float4) ----
  for (int i = tid; i < 4 * T / 4; i += TPB) {
    const int xb = i >> 7, tq = i & 127;
    float4 v = ((const float4*)(xg + (size_t)(b0 + xb) * T))[tq];
    *(float4*)&xs[xb][tq * 4] = v;
  }
  // ---- zero h buffers ----
  for (int i = tid; i < 4 * HSTR; i += TPB) { hs0[i] = 0.0f; hs1[i] = 0.0f; }

  // ---- per-lane W tile: 4 gates x 16 k = 16 float4 = 64 VGPRs ----
  float4 w0[4], w1[4], w2[4], w3[4];
#pragma unroll
  for (int j = 0; j < 4; ++j) {
    w0[j] = *(const float4*)(W_hh + (0 * H + u) * H + q * 16 + j * 4);
    w1[j] = *(const float4*)(W_hh + (1 * H + u) * H + q * 16 + j * 4);
    w2[j] = *(const float4*)(W_hh + (2 * H + u) * H + q * 16 + j * 4);
    w3[j] = *(const float4*)(W_hh + (3 * H + u) * H + q * 16 + j * 4);
  }
  const float wih0 = W_ih[u],         wih1 = W_ih[H + u];
  const float wih2 = W_ih[2 * H + u], wih3 = W_ih[3 * H + u];
  const float bia0 = b_ih[u] + b_hh[u];
  const float bia1 = b_ih[H + u] + b_hh[H + u];
  const float bia2 = b_ih[2 * H + u] + b_hh[2 * H + u];
  const float bia3 = b_ih[3 * H + u] + b_hh[3 * H + u];

  const int    qoff = q * 16;        // this lane's k-slice offset
  const int    hwix = q * HSTR + u;  // this lane's h write index (batch q, unit u)
  const float* xq   = &xs[q][0];
  const bool   qa   = (q & 1) != 0;
  const bool   qb   = (q & 2) != 0;

  float c = 0.0f;

  __syncthreads();

#define LSTM_STEP(HSRC, HDST, TT)                                             \
  {                                                                           \
    const float* hb = (HSRC) + qoff;                                          \
    float acc[4][4];                                                          \
    _Pragma("unroll") for (int g = 0; g < 4; ++g)                             \
      _Pragma("unroll") for (int b = 0; b < 4; ++b) acc[g][b] = 0.0f;         \
    _Pragma("unroll") for (int b = 0; b < 4; ++b) {                           \
      _Pragma("unroll") for (int j = 0; j < 4; ++j) {                         \
        const float4 h4 = *(const float4*)(hb + b * HSTR + j * 4);            \
        acc[0][b] = dot4(w0[j], h4, acc[0][b]);                               \
        acc[1][b] = dot4(w1[j], h4, acc[1][b]);                               \
        acc[2][b] = dot4(w2[j], h4, acc[2][b]);                               \
        acc[3][b] = dot4(w3[j], h4, acc[3][b]);                               \
      }                                                                       \
    }                                                                         \
    /* reduce across k-quarters (the quad) -> every lane has full sums */     \
    _Pragma("unroll") for (int g = 0; g < 4; ++g)                             \
      _Pragma("unroll") for (int b = 0; b < 4; ++b) {                         \
        acc[g][b] = qadd<QP_XOR1>(acc[g][b]);                                 \
        acc[g][b] = qadd<QP_XOR2>(acc[g][b]);                                 \
      }                                                                       \
    /* pick this lane's batch column (b == q) */                              \
    const float d0 = qb ? (qa ? acc[0][3] : acc[0][2]) : (qa ? acc[0][1] : acc[0][0]); \
    const float d1 = qb ? (qa ? acc[1][3] : acc[1][2]) : (qa ? acc[1][1] : acc[1][0]); \
    const float d2 = qb ? (qa ? acc[2][3] : acc[2][2]) : (qa ? acc[2][1] : acc[2][0]); \
    const float d3 = qb ? (qa ? acc[3][3] : acc[3][2]) : (qa ? acc[3][1] : acc[3][0]); \
    const float xt = xq[(TT)];                                                \
    const float a0 = fmaf(xt, wih0, d0 + bia0);                               \
    const float a1 = fmaf(xt, wih1, d1 + bia1);                               \
    const float a2 = fmaf(xt, wih2, d2 + bia2);                               \
    const float a3 = fmaf(xt, wih3, d3 + bia3);                               \
    const float ig = fsig(a0);                                                \
    const float fg = fsig(a1);                                                \
    const float gg = ftanh(a2);                                               \
    const float og = fsig(a3);                                                \
    c = fmaf(fg, c, ig * gg);                                                 \
    (HDST)[hwix] = og * ftanh(c);                                             \
    __syncthreads();                                                          \
  }

  for (int t = 0; t < T; t += 2) {
    LSTM_STEP(hs0, hs1, t);
    LSTM_STEP(hs1, hs0, t + 1);
  }
#undef LSTM_STEP

  // final h is in hs0 (T even). Head: relu(h@fc1^T+b1) @ fc2^T + b2
  if (tid < 64) {
    const int bq = tid >> 4;
    const int j2 = tid & 15;
    float s = fc1_b[j2];
    const float* fw = fc1_w + j2 * H;
#pragma unroll
    for (int k = 0; k < H; ++k) s = fmaf(hs0[bq * HSTR + k], fw[k], s);
    s = fmaxf(s, 0.0f);
    zs[bq][j2] = s * fc2_w[j2];
  }
  __syncthreads();
  if (tid < 4) {
    float s = fc2_b[0];
#pragma unroll
    for (int j = 0; j < 16; ++j) s += zs[tid][j];
    out[b0 + tid] = s;
  }
}

}  // namespace

extern "C" void kernel_launch(void* const* d_in, const int* in_sizes, int n_in,
                              void* d_out, int out_size, void* d_ws, size_t ws_size,
                              hipStream_t stream) {
  const float* xg    = (const float*)d_in[0];
  const float* W_ih  = (const float*)d_in[1];
  const float* W_hh  = (const float*)d_in[2];
  const float* b_ih  = (const float*)d_in[3];
  const float* b_hh  = (const float*)d_in[4];
  const float* fc1_w = (const float*)d_in[5];
  const float* fc1_b = (const float*)d_in[6];
  const float* fc2_w = (const float*)d_in[7];
  const float* fc2_b = (const float*)d_in[8];
  float* out = (float*)d_out;

  dim3 grid(2048 / 4);   // 512 blocks -> 2 per CU
  dim3 block(TPB);
  hipLaunchKernelGGL(lstm_fused, grid, block, 0, stream,
                     xg, W_ih, W_hh, b_ih, b_hh, fc1_w, fc1_b, fc2_w, fc2_b, out);
}

// Round 3
// 707.058 us; speedup vs baseline: 1.3668x; 1.0188x over previous
//
#include <hip/hip_runtime.h>

namespace {

constexpr int T    = 512;   // sequence length
constexpr int H    = 64;    // hidden units
constexpr int TPB  = 256;   // 4 waves
constexpr int HSTR = 68;    // h row stride in floats (pad: 68*4B = 17*16B, 16B-aligned)

// DPP quad_perm controls: ctrl = a | b<<2 | c<<4 | d<<6
constexpr int QP_XOR1 = 0xB1;  // [1,0,3,2]
constexpr int QP_XOR2 = 0x4E;  // [2,3,0,1]

__device__ __forceinline__ float fsig(float x) {
  return __builtin_amdgcn_rcpf(1.0f + __expf(-x));
}
__device__ __forceinline__ float ftanh(float x) {
  return fmaf(-2.0f, __builtin_amdgcn_rcpf(1.0f + __expf(2.0f * x)), 1.0f);
}
__device__ __forceinline__ float dot4(float4 w, float4 h, float a) {
  a = fmaf(w.x, h.x, a);
  a = fmaf(w.y, h.y, a);
  a = fmaf(w.z, h.z, a);
  return fmaf(w.w, h.w, a);
}
// v += value-from-lane (lane ^ mask within quad); VALU-pipe cross-lane (no LDS)
template <int CTRL>
__device__ __forceinline__ float qadd(float v) {
  int x = __builtin_amdgcn_update_dpp(0, __float_as_int(v), CTRL, 0xf, 0xf, true);
  return v + __int_as_float(x);
}
// Pin a float4 into VGPRs: makes the value opaque so the backend cannot
// rematerialize the originating global load inside the T-loop.
// (R2 evidence: VGPR_Count=84 + FETCH_SIZE=2.4GB -> W was re-loaded per step.)
__device__ __forceinline__ void pin4(float4& v) {
  asm volatile("" : "+v"(v.x), "+v"(v.y), "+v"(v.z), "+v"(v.w));
}
__device__ __forceinline__ void pin1(float& v) { asm volatile("" : "+v"(v)); }

// grid 512 x block 256; block = 4 batches x 64 units.
// thread: u = tid>>2 (unit), q = tid&3 (k-quarter AND batch for the c/h state).
// W_hh rows {u,64+u,128+u,192+u} x k in [16q,16q+16) live in 64 VGPRs per lane
// (pinned). Per step: 16 ds_read_b128 (h slices), quad_perm DPP butterfly
// reduction (VALU), 1 ds_write_b32, 1 barrier.
__global__ __launch_bounds__(TPB, 2)
void lstm_fused(const float* __restrict__ xg,
                const float* __restrict__ W_ih,
                const float* __restrict__ W_hh,
                const float* __restrict__ b_ih,
                const float* __restrict__ b_hh,
                const float* __restrict__ fc1_w,
                const float* __restrict__ fc1_b,
                const float* __restrict__ fc2_w,
                const float* __restrict__ fc2_b,
                float* __restrict__ out)
{
  __shared__ __align__(16) float hs0[4 * HSTR];   // h double-buffer, layout [b][HSTR]
  __shared__ __align__(16) float hs1[4 * HSTR];
  __shared__ __align__(16) float xs[4][T + 4];    // +4 pad -> xs[q][t] reads hit 4 banks
  __shared__ float zs[4][16];

  const int tid = threadIdx.x;
  const int b0  = blockIdx.x * 4;
  const int u   = tid >> 2;
  const int q   = tid & 3;

  // ---- stage x (coalesced float4) ----
  for (int i = tid; i < 4 * T / 4; i += TPB) {
    const int xb = i >> 7, tq = i & 127;
    float4 v = ((const float4*)(xg + (size_t)(b0 + xb) * T))[tq];
    *(float4*)&xs[xb][tq * 4] = v;
  }
  // ---- zero h buffers ----
  for (int i = tid; i < 4 * HSTR; i += TPB) { hs0[i] = 0.0f; hs1[i] = 0.0f; }

  // ---- per-lane W tile: 4 gates x 16 k = 16 float4 = 64 VGPRs, pinned ----
  float4 w0[4], w1[4], w2[4], w3[4];
#pragma unroll
  for (int j = 0; j < 4; ++j) {
    w0[j] = *(const float4*)(W_hh + (0 * H + u) * H + q * 16 + j * 4);
    w1[j] = *(const float4*)(W_hh + (1 * H + u) * H + q * 16 + j * 4);
    w2[j] = *(const float4*)(W_hh + (2 * H + u) * H + q * 16 + j * 4);
    w3[j] = *(const float4*)(W_hh + (3 * H + u) * H + q * 16 + j * 4);
    pin4(w0[j]); pin4(w1[j]); pin4(w2[j]); pin4(w3[j]);
  }
  float wih0 = W_ih[u],         wih1 = W_ih[H + u];
  float wih2 = W_ih[2 * H + u], wih3 = W_ih[3 * H + u];
  float bia0 = b_ih[u] + b_hh[u];
  float bia1 = b_ih[H + u] + b_hh[H + u];
  float bia2 = b_ih[2 * H + u] + b_hh[2 * H + u];
  float bia3 = b_ih[3 * H + u] + b_hh[3 * H + u];
  pin1(wih0); pin1(wih1); pin1(wih2); pin1(wih3);
  pin1(bia0); pin1(bia1); pin1(bia2); pin1(bia3);

  const int    qoff = q * 16;        // this lane's k-slice offset
  const int    hwix = q * HSTR + u;  // this lane's h write index (batch q, unit u)
  const float* xq   = &xs[q][0];
  const bool   qa   = (q & 1) != 0;
  const bool   qb   = (q & 2) != 0;

  float c = 0.0f;

  __syncthreads();

#define LSTM_STEP(HSRC, HDST, TT)                                             \
  {                                                                           \
    const float* hb = (HSRC) + qoff;                                          \
    float acc[4][4];                                                          \
    _Pragma("unroll") for (int g = 0; g < 4; ++g)                             \
      _Pragma("unroll") for (int b = 0; b < 4; ++b) acc[g][b] = 0.0f;         \
    _Pragma("unroll") for (int b = 0; b < 4; ++b) {                           \
      _Pragma("unroll") for (int j = 0; j < 4; ++j) {                         \
        const float4 h4 = *(const float4*)(hb + b * HSTR + j * 4);            \
        acc[0][b] = dot4(w0[j], h4, acc[0][b]);                               \
        acc[1][b] = dot4(w1[j], h4, acc[1][b]);                               \
        acc[2][b] = dot4(w2[j], h4, acc[2][b]);                               \
        acc[3][b] = dot4(w3[j], h4, acc[3][b]);                               \
      }                                                                       \
    }                                                                         \
    /* reduce across k-quarters (the quad) -> every lane has full sums */     \
    _Pragma("unroll") for (int g = 0; g < 4; ++g)                             \
      _Pragma("unroll") for (int b = 0; b < 4; ++b) {                         \
        acc[g][b] = qadd<QP_XOR1>(acc[g][b]);                                 \
        acc[g][b] = qadd<QP_XOR2>(acc[g][b]);                                 \
      }                                                                       \
    /* pick this lane's batch column (b == q) */                              \
    const float d0 = qb ? (qa ? acc[0][3] : acc[0][2]) : (qa ? acc[0][1] : acc[0][0]); \
    const float d1 = qb ? (qa ? acc[1][3] : acc[1][2]) : (qa ? acc[1][1] : acc[1][0]); \
    const float d2 = qb ? (qa ? acc[2][3] : acc[2][2]) : (qa ? acc[2][1] : acc[2][0]); \
    const float d3 = qb ? (qa ? acc[3][3] : acc[3][2]) : (qa ? acc[3][1] : acc[3][0]); \
    const float xt = xq[(TT)];                                                \
    const float a0 = fmaf(xt, wih0, d0 + bia0);                               \
    const float a1 = fmaf(xt, wih1, d1 + bia1);                               \
    const float a2 = fmaf(xt, wih2, d2 + bia2);                               \
    const float a3 = fmaf(xt, wih3, d3 + bia3);                               \
    const float ig = fsig(a0);                                                \
    const float fg = fsig(a1);                                                \
    const float gg = ftanh(a2);                                               \
    const float og = fsig(a3);                                                \
    c = fmaf(fg, c, ig * gg);                                                 \
    (HDST)[hwix] = og * ftanh(c);                                             \
    __syncthreads();                                                          \
  }

  for (int t = 0; t < T; t += 2) {
    LSTM_STEP(hs0, hs1, t);
    LSTM_STEP(hs1, hs0, t + 1);
  }
#undef LSTM_STEP

  // final h is in hs0 (T even). Head: relu(h@fc1^T+b1) @ fc2^T + b2
  if (tid < 64) {
    const int bq = tid >> 4;
    const int j2 = tid & 15;
    float s = fc1_b[j2];
    const float* fw = fc1_w + j2 * H;
#pragma unroll
    for (int k = 0; k < H; ++k) s = fmaf(hs0[bq * HSTR + k], fw[k], s);
    s = fmaxf(s, 0.0f);
    zs[bq][j2] = s * fc2_w[j2];
  }
  __syncthreads();
  if (tid < 4) {
    float s = fc2_b[0];
#pragma unroll
    for (int j = 0; j < 16; ++j) s += zs[tid][j];
    out[b0 + tid] = s;
  }
}

}  // namespace

extern "C" void kernel_launch(void* const* d_in, const int* in_sizes, int n_in,
                              void* d_out, int out_size, void* d_ws, size_t ws_size,
                              hipStream_t stream) {
  const float* xg    = (const float*)d_in[0];
  const float* W_ih  = (const float*)d_in[1];
  const float* W_hh  = (const float*)d_in[2];
  const float* b_ih  = (const float*)d_in[3];
  const float* b_hh  = (const float*)d_in[4];
  const float* fc1_w = (const float*)d_in[5];
  const float* fc1_b = (const float*)d_in[6];
  const float* fc2_w = (const float*)d_in[7];
  const float* fc2_b = (const float*)d_in[8];
  float* out = (float*)d_out;

  dim3 grid(2048 / 4);   // 512 blocks -> 2 per CU
  dim3 block(TPB);
  hipLaunchKernelGGL(lstm_fused, grid, block, 0, stream,
                     xg, W_ih, W_hh, b_ih, b_hh, fc1_w, fc1_b, fc2_w, fc2_b, out);
}